// Round 5
// baseline (220.053 us; speedup 1.0000x reference)
//
#include <hip/hip_runtime.h>
#include <stdint.h>

typedef unsigned short u16;
typedef short short8 __attribute__((ext_vector_type(8)));
typedef short short4v __attribute__((ext_vector_type(4)));
typedef float float4v __attribute__((ext_vector_type(4)));
typedef float float16v __attribute__((ext_vector_type(16)));
typedef uint32_t uint2v __attribute__((ext_vector_type(2)));

#define HW 4096
#define QSCL 0.18033688011112042f   /* 0.125 * log2(e), folded into Q at conv time */

// async global->LDS DMA: per-lane global addr, LDS dest = wave-uniform base + lane*16
#define GLOAD_LDS(g, l) __builtin_amdgcn_global_load_lds( \
    (const __attribute__((address_space(1))) void*)(g),   \
    (__attribute__((address_space(3))) void*)(l), 16, 0, 0)

static __device__ __forceinline__ u16 f2bf(float f) {
  union { float f; uint32_t u; } v; v.f = f;
  uint32_t r = v.u + 0x7fffu + ((v.u >> 16) & 1u);
  return (u16)(r >> 16);
}

// packed f32x2 -> bf16x2 (RNE), single instruction; src0 -> low half
static __device__ __forceinline__ uint32_t pkbf(float a, float b) {
  uint32_t r;
  asm("v_cvt_pk_bf16_f32 %0, %1, %2" : "=v"(r) : "v"(a), "v"(b));
  return r;
}

// ---- kernel 1: x [4,256,4096] f32 -> Xtp [4,66,66,256] bf16 (spatially padded; halo pre-zeroed)
__global__ __launch_bounds__(256) void k_xt(const float* __restrict__ x, u16* __restrict__ Xtp) {
  __shared__ float t[32][33];
  const int b = blockIdx.z, c0 = blockIdx.y * 32, p0 = blockIdx.x * 32;
  const int tid = threadIdx.x;
  const int l8 = tid >> 5, lp = tid & 31;
#pragma unroll
  for (int i = 0; i < 4; i++) {
    int c = l8 + i * 8;
    t[c][lp] = x[(size_t)(b * 256 + c0 + c) * HW + p0 + lp];
  }
  __syncthreads();
#pragma unroll
  for (int i = 0; i < 4; i++) {
    int p = l8 + i * 8;
    int pp = p0 + p;
    int y = pp >> 6, xx = pp & 63;
    Xtp[((size_t)(b * 66 + y + 1) * 66 + (xx + 1)) * 256 + c0 + lp] = f2bf(t[lp][p]);
  }
}

// ---- kernel 2: repack weights -> Wt [9][384][256] bf16 (ci contiguous), bcat[384] f32
__global__ __launch_bounds__(256) void k_wprep(const float* __restrict__ qw, const float* __restrict__ qb,
    const float* __restrict__ kw, const float* __restrict__ kb,
    const float* __restrict__ vw, const float* __restrict__ vb,
    u16* __restrict__ Wt, float* __restrict__ bcat) {
  int tid = blockIdx.x * 256 + threadIdx.x;
  if (tid < 9 * 384 * 256) {
    int ci = tid & 255;
    int n = (tid >> 8) % 384;
    int off = tid / (384 * 256);
    float val;
    if (n < 64)       val = qw[(size_t)n * 2304 + ci * 9 + off];
    else if (n < 128) val = kw[(size_t)(n - 64) * 2304 + ci * 9 + off];
    else              val = vw[(size_t)(n - 128) * 2304 + ci * 9 + off];
    Wt[tid] = f2bf(val);
  }
  if (tid < 384) bcat[tid] = (tid < 64) ? qb[tid] : (tid < 128) ? kb[tid - 64] : vb[tid - 128];
}

// ---- kernel 3: fused QKV conv (proven structure; Q outputs pre-scaled by QSCL).
__global__ __launch_bounds__(256) void k_conv(const u16* __restrict__ Xtp,
    const u16* __restrict__ Wt, const float* __restrict__ bcat,
    u16* __restrict__ Qt, u16* __restrict__ Kt, u16* __restrict__ Vcf) {
  __shared__ __align__(16) u16 Als[2][128 * 64];   // 16 KB per buf [row pos][64 k]
  __shared__ __align__(16) u16 Bls[2][64 * 64];    // 8 KB per buf  [row ch ][64 k]
  const int tid = threadIdx.x;
  const int b = blockIdx.z, ct = blockIdx.y;       // ct: 0=Q, 1=K, 2..5=V slices
  const int p0 = blockIdx.x * 128, n0 = ct * 64;
  const int w = tid >> 6, lane = tid & 63, l16 = lane & 15, quad = lane >> 4;

  const int lr = lane >> 3, lcx = (lane & 7) ^ lr;
  const u16* ag[4];
#pragma unroll
  for (int g = 0; g < 4; g++) {
    const int pos = p0 + w * 32 + g * 8 + lr;
    const int py = pos >> 6, px = pos & 63;
    ag[g] = Xtp + ((size_t)(b * 66 + py) * 66 + px) * 256 + lcx * 8;
  }
  const u16* bg[2];
#pragma unroll
  for (int g = 0; g < 2; g++)
    bg[g] = Wt + (size_t)(n0 + w * 16 + g * 8 + lr) * 256 + lcx * 8;

  const int rx = l16 & 7;

  float4v acc[2][4];
  const float4v zz = {0.f, 0.f, 0.f, 0.f};
#pragma unroll
  for (int i = 0; i < 2; i++)
#pragma unroll
    for (int j = 0; j < 4; j++) acc[i][j] = zz;

#pragma unroll
  for (int g = 0; g < 4; g++) GLOAD_LDS(ag[g], &Als[0][(w * 32 + g * 8) * 64]);
#pragma unroll
  for (int g = 0; g < 2; g++) GLOAD_LDS(bg[g], &Bls[0][(w * 16 + g * 8) * 64]);
  __syncthreads();

  for (int ks = 0; ks < 36; ks++) {
    const int buf = ks & 1;
    if (ks + 1 < 36) {
      const int ksn = ks + 1, tap = ksn >> 2, cg = (ksn & 3) * 64;
      const int dy = (tap * 11) >> 5, dx = tap - dy * 3;
      const int aoff = (dy * 66 + dx) * 256 + cg;
      const size_t boff = (size_t)tap * 98304 + cg;
#pragma unroll
      for (int g = 0; g < 4; g++) GLOAD_LDS(ag[g] + aoff, &Als[buf ^ 1][(w * 32 + g * 8) * 64]);
#pragma unroll
      for (int g = 0; g < 2; g++) GLOAD_LDS(bg[g] + boff, &Bls[buf ^ 1][(w * 16 + g * 8) * 64]);
    }

    short8 af[2][2], bfv[4][2];
#pragma unroll
    for (int mt = 0; mt < 2; mt++)
#pragma unroll
      for (int kk = 0; kk < 2; kk++)
        af[mt][kk] = *(const short8*)&Als[buf][(w * 32 + mt * 16 + l16) * 64 + (((kk * 4 + quad) ^ rx) * 8)];
#pragma unroll
    for (int nt = 0; nt < 4; nt++)
#pragma unroll
      for (int kk = 0; kk < 2; kk++)
        bfv[nt][kk] = *(const short8*)&Bls[buf][(nt * 16 + l16) * 64 + (((kk * 4 + quad) ^ rx) * 8)];

    if (ct < 2) {
#pragma unroll
      for (int mt = 0; mt < 2; mt++)
#pragma unroll
        for (int nt = 0; nt < 4; nt++)
#pragma unroll
          for (int kk = 0; kk < 2; kk++)
            acc[mt][nt] = __builtin_amdgcn_mfma_f32_16x16x32_bf16(bfv[nt][kk], af[mt][kk], acc[mt][nt], 0, 0, 0);
    } else {
#pragma unroll
      for (int mt = 0; mt < 2; mt++)
#pragma unroll
        for (int nt = 0; nt < 4; nt++)
#pragma unroll
          for (int kk = 0; kk < 2; kk++)
            acc[mt][nt] = __builtin_amdgcn_mfma_f32_16x16x32_bf16(af[mt][kk], bfv[nt][kk], acc[mt][nt], 0, 0, 0);
    }
    __syncthreads();
  }

  if (ct < 2) {
    u16* base = (ct == 0) ? Qt : Kt;
    const float qs = (ct == 0) ? QSCL : 1.0f;
#pragma unroll
    for (int mt = 0; mt < 2; mt++) {
      const int p = p0 + w * 32 + mt * 16 + l16;
#pragma unroll
      for (int nt = 0; nt < 4; nt++) {
        const int nb = nt * 16 + quad * 4;
        short4v o;
#pragma unroll
        for (int r = 0; r < 4; r++) o[r] = (short)f2bf((acc[mt][nt][r] + bcat[ct * 64 + nb + r]) * qs);
        *(short4v*)(base + (size_t)(b * HW + p) * 64 + nb) = o;
      }
    }
  } else {
#pragma unroll
    for (int mt = 0; mt < 2; mt++) {
      const int pb = p0 + w * 32 + mt * 16 + quad * 4;
#pragma unroll
      for (int nt = 0; nt < 4; nt++) {
        const int cl = nt * 16 + l16;
        const int gc = (ct - 2) * 64 + cl;
        const float bias = bcat[ct * 64 + cl];
        short4v o;
#pragma unroll
        for (int r = 0; r < 4; r++) o[r] = (short)f2bf(acc[mt][nt][r] + bias);
        *(short4v*)(Vcf + (size_t)(b * 256 + gc) * HW + pb) = o;
      }
    }
  }
}

// ---- kernel 4: flash attention, R5 = true 2-blocks/CU co-residency.
// R4 lesson: single barrier didn't help because 137KB LDS -> 1 block/CU ->
// the barrier still rendezvouses everything on one critical path (3530 cyc/iter
// vs ~1600 cyc of actual pipe work). R5:
//   * q-tile 32 -> grid 512 = 2 blocks/CU = 16 waves/CU; independent blocks
//     fill each other's barrier/drain gaps.
//   * K global->REG (prefetch 2 iters ahead, static rotation via 2x-unrolled
//     loop): A-frag is 16B/lane over a 2KB span (well-coalesced, L2-resident
//     after XCD pinning) — kills K's LDS slots AND its LDS reads.
//   * LDS = V dbuf 64K + P dbuf 8K + Lsm 0.5K = 74KB -> 2 blocks fit.
//   * one __syncthreads/iter: V-DMA(t+1) post-barrier into buffer whose readers
//     (PV(t-1)) provably passed barrier(t); P dbuf same proof as R4.
// Per S-wave (jb=w&3, ih=w>>2): 2 MFMA 16x16x32, 4 exps, 1 b64 P write.
// Per PV wave (32c x 32i): 4 V + 4 P b128 reads, 4 MFMA 32x32x16, of=16 f32.
__global__ __launch_bounds__(512, 4) void k_attn(const u16* __restrict__ Qt,
    const u16* __restrict__ Kt, const u16* __restrict__ Vcf, float* __restrict__ out) {
  __shared__ __align__(16) u16 Vls[2][256 * 64];   // 64 KB [c][j] swizzled, dbuf
  __shared__ __align__(16) u16 Pls[2][32 * 64];    //  8 KB [i][j] swizzled, dbuf
  __shared__ float Lsm[4][32];                     // per-jb partial row sums

  const int tid = threadIdx.x;
  const int bid = blockIdx.x;
  const int b = bid & 3, q0 = (bid >> 2) * 32;     // XCD k -> batch k&3 (L2 pin)
  const int w = tid >> 6, lane = tid & 63;
  const int l16 = lane & 15, quad = lane >> 4;
  const int l32 = lane & 31, half = lane >> 5;
  const int jb = w & 3, ih = w >> 2;   // S-phase: wave w -> 16 j x 16 i
  // PV-phase: wave w -> channels w*32..w*32+31, all 32 i

  const u16* Kb = Kt + (size_t)b * HW * 64;
  const char* Vb = (const char*)(Vcf + (size_t)b * 256 * HW);

  // V staging lane constants: 8 rows x 8 chunks(16B); global chunk = (lane&7)^row
  const int lr = lane >> 3, lcx = (lane & 7) ^ lr;
  const char* vbase = Vb + (size_t)(w * 32 + lr) * (HW * 2) + lcx * 16;

  // K global->reg fragment base: A[m=j=jb*16+l16][k=d=quad*8+e], + jt*4096 + kk*32
  const u16* kgp = Kb + (size_t)(jb * 16 + l16) * 64 + quad * 8;

  // P write offset (u16): row i = ih*16+l16, chunk (jb*2+(quad>>1))^(row&7)
  const int pw = (ih * 16 + l16) * 64 + (((jb * 2 + (quad >> 1)) ^ (l16 & 7)) * 8) + (quad & 1) * 4;

  // PV read offsets (u16): V row c = w*32+l32; P row i = l32; chunk (jk*2+half)^(row&7)
  const int vrow = (w * 32 + l32) * 64;
  const int prow = l32 * 64;
  const int rx5 = l32 & 7;

  // Q as B-operand: B[k=d][n=i], rows i = q0 + ih*16 + l16 (pre-scaled by QSCL)
  short8 qf0, qf1;
  {
    const u16* qp = Qt + ((size_t)(b * HW + q0 + ih * 16 + l16)) * 64 + quad * 8;
    qf0 = *(const short8*)qp;
    qf1 = *(const short8*)(qp + 32);
  }

  float16v of;
#pragma unroll
  for (int r = 0; r < 16; r++) of[r] = 0.f;
  float lp = 0.f;
  const float4v zz = {0.f, 0.f, 0.f, 0.f};

  // ---- prologue: stage V tile 0 -> buf 0; K frags for jt=0 (A) and jt=1 (B)
#pragma unroll
  for (int g = 0; g < 4; g++)
    GLOAD_LDS(vbase + (size_t)(g * 8) * (HW * 2), &Vls[0][(w * 32 + g * 8) * 64]);
  short8 kfA0 = *(const short8*)(kgp);
  short8 kfA1 = *(const short8*)(kgp + 32);
  short8 kfB0 = *(const short8*)(kgp + 4096);
  short8 kfB1 = *(const short8*)(kgp + 4096 + 32);
  __syncthreads();

  // one iteration; P = buffer parity (0 for even jt, 1 for odd), KF0/KF1 = K frags
#define ATTN_ITER(JT, PAR, KF0, KF1)                                           \
  {                                                                            \
    /* S^T: lane holds S^T[j=jb*16+quad*4+r][i=ih*16+l16] */                   \
    float4v s = zz;                                                            \
    s = __builtin_amdgcn_mfma_f32_16x16x32_bf16(KF0, qf0, s, 0, 0, 0);         \
    s = __builtin_amdgcn_mfma_f32_16x16x32_bf16(KF1, qf1, s, 0, 0, 0);         \
    /* P = exp2(S); pack; swizzled write; per-lane partial sum */              \
    float p0 = exp2f(s[0]), p1 = exp2f(s[1]), p2 = exp2f(s[2]), p3 = exp2f(s[3]); \
    lp += (p0 + p1) + (p2 + p3);                                               \
    uint2v pd; pd[0] = pkbf(p0, p1); pd[1] = pkbf(p2, p3);                     \
    *(uint2v*)&Pls[PAR][pw] = pd;                                              \
    /* the ONE barrier: P visible; V DMA for this tile landed */               \
    __syncthreads();                                                           \
    /* refill this parity's K frags for jt+2 (consumed 2 iters from now) */    \
    {                                                                          \
      const u16* kp2 = kgp + (size_t)(((JT) + 2) & 63) * 4096;                 \
      KF0 = *(const short8*)(kp2);                                             \
      KF1 = *(const short8*)(kp2 + 32);                                        \
    }                                                                          \
    /* V DMA for jt+1 into buf PAR^1 (readers finished before this barrier) */ \
    {                                                                          \
      const char* vt = vbase + (size_t)(((JT) + 1) & 63) * 128;                \
      for (int g = 0; g < 4; g++)                                              \
        GLOAD_LDS(vt + (size_t)(g * 8) * (HW * 2), &Vls[PAR ^ 1][(w * 32 + g * 8) * 64]); \
    }                                                                          \
    /* O^T += V P : D[m=c][n=i=l32] */                                         \
    __builtin_amdgcn_s_setprio(1);                                             \
    _Pragma("unroll")                                                          \
    for (int jk = 0; jk < 4; jk++) {                                           \
      const int co = ((jk * 2 + half) ^ rx5) * 8;                              \
      short8 vf = *(const short8*)&Vls[PAR][vrow + co];                        \
      short8 pf = *(const short8*)&Pls[PAR][prow + co];                        \
      of = __builtin_amdgcn_mfma_f32_32x32x16_bf16(vf, pf, of, 0, 0, 0);       \
    }                                                                          \
    __builtin_amdgcn_s_setprio(0);                                             \
  }

  for (int jt = 0; jt < 64; jt += 2) {
    ATTN_ITER(jt, 0, kfA0, kfA1);
    ATTN_ITER(jt + 1, 1, kfB0, kfB1);
  }
#undef ATTN_ITER

  // ---- epilogue: finish row sums (quad reduce + cross-jb via LDS), scale, store
  lp += __shfl_xor(lp, 16);
  lp += __shfl_xor(lp, 32);
  if (quad == 0) Lsm[jb][ih * 16 + l16] = lp;
  __syncthreads();

  const float inv = 1.0f / ((Lsm[0][l32] + Lsm[1][l32]) + (Lsm[2][l32] + Lsm[3][l32]));
  float* ob = out + ((size_t)(b * 256 + w * 32 + 4 * half)) * HW + q0 + l32;
#pragma unroll
  for (int r = 0; r < 16; r++)
    ob[(size_t)((r & 3) + 8 * (r >> 2)) * HW] = of[r] * inv;
}

extern "C" void kernel_launch(void* const* d_in, const int* in_sizes, int n_in,
                              void* d_out, int out_size, void* d_ws, size_t ws_size,
                              hipStream_t stream) {
  const float* x  = (const float*)d_in[0];
  const float* qw = (const float*)d_in[1];
  const float* qb = (const float*)d_in[2];
  const float* kw = (const float*)d_in[3];
  const float* kb = (const float*)d_in[4];
  const float* vw = (const float*)d_in[5];
  const float* vb = (const float*)d_in[6];
  float* out = (float*)d_out;
  char* ws = (char*)d_ws;
  u16*   Xtp = (u16*)(ws);
  u16*   Wt  = (u16*)(ws + 8921088);
  float* bc  = (float*)(ws + 10690560);
  u16*   Qt  = (u16*)(ws + 10692096);
  u16*   Kt  = (u16*)(ws + 12789248);
  u16*   Vcf = (u16*)(ws + 14886400);

  hipMemsetAsync(Xtp, 0, 8921088, stream);  // zero the spatial halo
  k_xt  <<<dim3(128, 8, 4), 256, 0, stream>>>(x, Xtp);
  k_wprep<<<3456, 256, 0, stream>>>(qw, qb, kw, kb, vw, vb, Wt, bc);
  k_conv<<<dim3(32, 6, 4), 256, 0, stream>>>(Xtp, Wt, bc, Qt, Kt, Vcf);
  k_attn<<<512, 512, 0, stream>>>(Qt, Kt, Vcf, out);
}

// Round 6
// 194.548 us; speedup vs baseline: 1.1311x; 1.1311x over previous
//
#include <hip/hip_runtime.h>
#include <stdint.h>

typedef unsigned short u16;
typedef short short8 __attribute__((ext_vector_type(8)));
typedef short short4v __attribute__((ext_vector_type(4)));
typedef float float4v __attribute__((ext_vector_type(4)));
typedef float float16v __attribute__((ext_vector_type(16)));
typedef uint32_t uint2v __attribute__((ext_vector_type(2)));

#define HW 4096
#define QSCL 0.18033688011112042f   /* 0.125 * log2(e), folded into Q at conv time */

// async global->LDS DMA: per-lane global addr, LDS dest = wave-uniform base + lane*16
#define GLOAD_LDS(g, l) __builtin_amdgcn_global_load_lds( \
    (const __attribute__((address_space(1))) void*)(g),   \
    (__attribute__((address_space(3))) void*)(l), 16, 0, 0)

static __device__ __forceinline__ u16 f2bf(float f) {
  union { float f; uint32_t u; } v; v.f = f;
  uint32_t r = v.u + 0x7fffu + ((v.u >> 16) & 1u);
  return (u16)(r >> 16);
}

// packed f32x2 -> bf16x2 (RNE), single instruction; src0 -> low half
static __device__ __forceinline__ uint32_t pkbf(float a, float b) {
  uint32_t r;
  asm("v_cvt_pk_bf16_f32 %0, %1, %2" : "=v"(r) : "v"(a), "v"(b));
  return r;
}
// v_permlane32_swap_b32: a.hi32lanes <-> b.lo32lanes (both regs modified)
static __device__ __forceinline__ void plswap(uint32_t &a, uint32_t &b) {
  asm("v_permlane32_swap_b32 %0, %1" : "+v"(a), "+v"(b));
}

union PU { uint32_t u[4]; short8 v; };

// ---- kernel 1: x [4,256,4096] f32 -> Xtp [4,66,66,256] bf16 (spatially padded; halo pre-zeroed)
__global__ __launch_bounds__(256) void k_xt(const float* __restrict__ x, u16* __restrict__ Xtp) {
  __shared__ float t[32][33];
  const int b = blockIdx.z, c0 = blockIdx.y * 32, p0 = blockIdx.x * 32;
  const int tid = threadIdx.x;
  const int l8 = tid >> 5, lp = tid & 31;
#pragma unroll
  for (int i = 0; i < 4; i++) {
    int c = l8 + i * 8;
    t[c][lp] = x[(size_t)(b * 256 + c0 + c) * HW + p0 + lp];
  }
  __syncthreads();
#pragma unroll
  for (int i = 0; i < 4; i++) {
    int p = l8 + i * 8;
    int pp = p0 + p;
    int y = pp >> 6, xx = pp & 63;
    Xtp[((size_t)(b * 66 + y + 1) * 66 + (xx + 1)) * 256 + c0 + lp] = f2bf(t[lp][p]);
  }
}

// ---- kernel 2: repack weights -> Wt [9][384][256] bf16 (ci contiguous), bcat[384] f32
__global__ __launch_bounds__(256) void k_wprep(const float* __restrict__ qw, const float* __restrict__ qb,
    const float* __restrict__ kw, const float* __restrict__ kb,
    const float* __restrict__ vw, const float* __restrict__ vb,
    u16* __restrict__ Wt, float* __restrict__ bcat) {
  int tid = blockIdx.x * 256 + threadIdx.x;
  if (tid < 9 * 384 * 256) {
    int ci = tid & 255;
    int n = (tid >> 8) % 384;
    int off = tid / (384 * 256);
    float val;
    if (n < 64)       val = qw[(size_t)n * 2304 + ci * 9 + off];
    else if (n < 128) val = kw[(size_t)(n - 64) * 2304 + ci * 9 + off];
    else              val = vw[(size_t)(n - 128) * 2304 + ci * 9 + off];
    Wt[tid] = f2bf(val);
  }
  if (tid < 384) bcat[tid] = (tid < 64) ? qb[tid] : (tid < 128) ? kb[tid - 64] : vb[tid - 128];
}

// ---- kernel 3: fused QKV conv (proven structure; Q outputs pre-scaled by QSCL).
__global__ __launch_bounds__(256) void k_conv(const u16* __restrict__ Xtp,
    const u16* __restrict__ Wt, const float* __restrict__ bcat,
    u16* __restrict__ Qt, u16* __restrict__ Kt, u16* __restrict__ Vcf) {
  __shared__ __align__(16) u16 Als[2][128 * 64];   // 16 KB per buf [row pos][64 k]
  __shared__ __align__(16) u16 Bls[2][64 * 64];    // 8 KB per buf  [row ch ][64 k]
  const int tid = threadIdx.x;
  const int b = blockIdx.z, ct = blockIdx.y;       // ct: 0=Q, 1=K, 2..5=V slices
  const int p0 = blockIdx.x * 128, n0 = ct * 64;
  const int w = tid >> 6, lane = tid & 63, l16 = lane & 15, quad = lane >> 4;

  const int lr = lane >> 3, lcx = (lane & 7) ^ lr;
  const u16* ag[4];
#pragma unroll
  for (int g = 0; g < 4; g++) {
    const int pos = p0 + w * 32 + g * 8 + lr;
    const int py = pos >> 6, px = pos & 63;
    ag[g] = Xtp + ((size_t)(b * 66 + py) * 66 + px) * 256 + lcx * 8;
  }
  const u16* bg[2];
#pragma unroll
  for (int g = 0; g < 2; g++)
    bg[g] = Wt + (size_t)(n0 + w * 16 + g * 8 + lr) * 256 + lcx * 8;

  const int rx = l16 & 7;

  float4v acc[2][4];
  const float4v zz = {0.f, 0.f, 0.f, 0.f};
#pragma unroll
  for (int i = 0; i < 2; i++)
#pragma unroll
    for (int j = 0; j < 4; j++) acc[i][j] = zz;

#pragma unroll
  for (int g = 0; g < 4; g++) GLOAD_LDS(ag[g], &Als[0][(w * 32 + g * 8) * 64]);
#pragma unroll
  for (int g = 0; g < 2; g++) GLOAD_LDS(bg[g], &Bls[0][(w * 16 + g * 8) * 64]);
  __syncthreads();

  for (int ks = 0; ks < 36; ks++) {
    const int buf = ks & 1;
    if (ks + 1 < 36) {
      const int ksn = ks + 1, tap = ksn >> 2, cg = (ksn & 3) * 64;
      const int dy = (tap * 11) >> 5, dx = tap - dy * 3;
      const int aoff = (dy * 66 + dx) * 256 + cg;
      const size_t boff = (size_t)tap * 98304 + cg;
#pragma unroll
      for (int g = 0; g < 4; g++) GLOAD_LDS(ag[g] + aoff, &Als[buf ^ 1][(w * 32 + g * 8) * 64]);
#pragma unroll
      for (int g = 0; g < 2; g++) GLOAD_LDS(bg[g] + boff, &Bls[buf ^ 1][(w * 16 + g * 8) * 64]);
    }

    short8 af[2][2], bfv[4][2];
#pragma unroll
    for (int mt = 0; mt < 2; mt++)
#pragma unroll
      for (int kk = 0; kk < 2; kk++)
        af[mt][kk] = *(const short8*)&Als[buf][(w * 32 + mt * 16 + l16) * 64 + (((kk * 4 + quad) ^ rx) * 8)];
#pragma unroll
    for (int nt = 0; nt < 4; nt++)
#pragma unroll
      for (int kk = 0; kk < 2; kk++)
        bfv[nt][kk] = *(const short8*)&Bls[buf][(nt * 16 + l16) * 64 + (((kk * 4 + quad) ^ rx) * 8)];

    if (ct < 2) {
#pragma unroll
      for (int mt = 0; mt < 2; mt++)
#pragma unroll
        for (int nt = 0; nt < 4; nt++)
#pragma unroll
          for (int kk = 0; kk < 2; kk++)
            acc[mt][nt] = __builtin_amdgcn_mfma_f32_16x16x32_bf16(bfv[nt][kk], af[mt][kk], acc[mt][nt], 0, 0, 0);
    } else {
#pragma unroll
      for (int mt = 0; mt < 2; mt++)
#pragma unroll
        for (int nt = 0; nt < 4; nt++)
#pragma unroll
          for (int kk = 0; kk < 2; kk++)
            acc[mt][nt] = __builtin_amdgcn_mfma_f32_16x16x32_bf16(af[mt][kk], bfv[nt][kk], acc[mt][nt], 0, 0, 0);
    }
    __syncthreads();
  }

  if (ct < 2) {
    u16* base = (ct == 0) ? Qt : Kt;
    const float qs = (ct == 0) ? QSCL : 1.0f;
#pragma unroll
    for (int mt = 0; mt < 2; mt++) {
      const int p = p0 + w * 32 + mt * 16 + l16;
#pragma unroll
      for (int nt = 0; nt < 4; nt++) {
        const int nb = nt * 16 + quad * 4;
        short4v o;
#pragma unroll
        for (int r = 0; r < 4; r++) o[r] = (short)f2bf((acc[mt][nt][r] + bcat[ct * 64 + nb + r]) * qs);
        *(short4v*)(base + (size_t)(b * HW + p) * 64 + nb) = o;
      }
    }
  } else {
#pragma unroll
    for (int mt = 0; mt < 2; mt++) {
      const int pb = p0 + w * 32 + mt * 16 + quad * 4;
#pragma unroll
      for (int nt = 0; nt < 4; nt++) {
        const int cl = nt * 16 + l16;
        const int gc = (ct - 2) * 64 + cl;
        const float bias = bcat[ct * 64 + cl];
        short4v o;
#pragma unroll
        for (int r = 0; r < 4; r++) o[r] = (short)f2bf(acc[mt][nt][r] + bias);
        *(short4v*)(Vcf + (size_t)(b * 256 + gc) * HW + pb) = o;
      }
    }
  }
}

// ---- kernel 4: flash attention, R6 = P-in-register (T12), no cross-wave softmax.
// Lesson R1/R4/R5: any structure handing P through LDS with a block barrier is
// stuck at ~0.4-0.9 cyc per (q x j) unit — cross-wave dependency serializes.
// R6: 256 blocks (1/CU, XCD-pinned) x 4 waves. Wave (qa=w&1, jh=w>>1) owns
// 32 q-rows (q0+qa*32) and j-half jh*2048 (no-max exp2 softmax => j-split
// partials just add; combined in epilogue via LDS).
// Per 32-j tile per wave, fully in-wave:
//   QK^T: 4x mfma_32x32x16(A=K_lds, B=Q_regs) -> lane holds S^T[16 j][i=l32]
//   P = exp2(S) in-lane; pack to PV B-frag via cvt_pk + permlane32_swap (T12):
//     D-row r -> j=(r&3)+8*(r>>2)+4*half; swap(pk(p0,p1),pk(p4,p5)) etc. yields
//     exactly B[k=j: half*8+e][n=i] — verified index algebra, 2 swaps/16 j.
//   PV: 16x mfma_32x32x16(A=V_lds, B=P_regs) -> of[8] (256 ch).
// K/V triple-buffered per j-stream (120 KB LDS total); per iter: counted
// s_waitcnt vmcnt(10) + raw s_barrier, THEN stage tile t+2 into the slot whose
// readers (compute t-1, both waves) provably passed the previous barrier.
// Staging split: wave qa stages half the stream's rows (2 K + 8 V DMAs).
__global__ __launch_bounds__(256, 1) void k_attn(const u16* __restrict__ Qt,
    const u16* __restrict__ Kt, const u16* __restrict__ Vcf, float* __restrict__ out) {
  __shared__ __align__(16) u16 lds[61440];   // 120 KB: 2 streams x {K 3x4KB, V 3x16KB}

  const int tid = threadIdx.x;
  const int bid = blockIdx.x;
  const int b = bid & 3;                     // XCD k -> batch k&3 (L2 pin)
  const int w = tid >> 6, lane = tid & 63;
  const int l32 = lane & 31, half = lane >> 5;
  const int qa = w & 1, jh = w >> 1;
  const int q0 = (bid >> 2) * 64 + qa * 32;

  u16* Sb = lds + jh * 30720;                // stream base (u16 units)

  const char* Kgb = (const char*)(Kt + (size_t)b * HW * 64);
  const char* Vgb = (const char*)(Vcf + (size_t)b * 256 * HW);

  // staging lane constants (pre-swizzled global source, linear LDS dest)
  const int lr = lane >> 3, lcx = (lane & 7) ^ lr;                 // K: 8 rows x 8 chunks
  const int vr = lane >> 2, vcx = (lane & 3) ^ ((lane >> 3) & 3);  // V: 16 rows x 4 chunks
  const char* ksrc = Kgb + ((size_t)(jh * 2048 + qa * 16 + lr)) * 128 + lcx * 16;
  const char* vsrc = Vgb + ((size_t)(qa * 128 + vr)) * 8192 + (size_t)(jh * 2048) * 2 + vcx * 16;

  // Q as B-operand: B[k=d=half*8+e (+16 per ks)][n=i=l32] (pre-scaled by QSCL)
  short8 qf[4];
  {
    const u16* qp = Qt + ((size_t)(b * HW + q0 + l32)) * 64 + half * 8;
#pragma unroll
    for (int ks = 0; ks < 4; ks++) qf[ks] = *(const short8*)(qp + ks * 16);
  }

  const int sw2 = (l32 >> 1) & 3;            // V read chunk swizzle
  const int kswz = l32 & 7;                  // K read chunk swizzle

  float16v of[8];
#pragma unroll
  for (int ct = 0; ct < 8; ct++)
#pragma unroll
    for (int r = 0; r < 16; r++) of[ct][r] = 0.f;
  float lp = 0.f;

#define STAGE(T, KS, VS) {                                                        \
    const size_t kb_ = (size_t)(T) * 4096;                                        \
    const size_t vb_ = (size_t)(T) * 64;                                          \
    _Pragma("unroll") for (int g = 0; g < 2; g++)                                 \
      GLOAD_LDS(ksrc + kb_ + g * 1024, &Sb[(KS) + qa * 1024 + g * 512]);          \
    _Pragma("unroll") for (int g = 0; g < 8; g++)                                 \
      GLOAD_LDS(vsrc + vb_ + (size_t)g * 131072, &Sb[(VS) + qa * 4096 + g * 512]);\
  }

#define COMPUTE() {                                                               \
    float16v s;                                                                   \
    _Pragma("unroll") for (int r = 0; r < 16; r++) s[r] = 0.f;                    \
    _Pragma("unroll") for (int ks = 0; ks < 4; ks++) {                            \
      short8 kf = *(const short8*)&Sb[kc + l32 * 64 + (((ks * 2 + half) ^ kswz) * 8)]; \
      s = __builtin_amdgcn_mfma_f32_32x32x16_bf16(kf, qf[ks], s, 0, 0, 0);        \
    }                                                                             \
    float p[16];                                                                  \
    _Pragma("unroll") for (int r = 0; r < 16; r++) p[r] = exp2f(s[r]);            \
    _Pragma("unroll") for (int r = 0; r < 16; r++) lp += p[r];                    \
    uint32_t c0 = pkbf(p[0], p[1]),  c1 = pkbf(p[2], p[3]);                       \
    uint32_t c2 = pkbf(p[4], p[5]),  c3 = pkbf(p[6], p[7]);                       \
    plswap(c0, c2); plswap(c1, c3);                                               \
    uint32_t d0 = pkbf(p[8], p[9]),  d1 = pkbf(p[10], p[11]);                     \
    uint32_t d2 = pkbf(p[12], p[13]), d3 = pkbf(p[14], p[15]);                    \
    plswap(d0, d2); plswap(d1, d3);                                               \
    PU pb0, pb1;                                                                  \
    pb0.u[0] = c0; pb0.u[1] = c1; pb0.u[2] = c2; pb0.u[3] = c3;                   \
    pb1.u[0] = d0; pb1.u[1] = d1; pb1.u[2] = d2; pb1.u[3] = d3;                   \
    _Pragma("unroll") for (int ct = 0; ct < 8; ct++) {                            \
      short8 vf0 = *(const short8*)&Sb[vc + ct * 1024 + l32 * 32 + ((half ^ sw2) * 8)]; \
      of[ct] = __builtin_amdgcn_mfma_f32_32x32x16_bf16(vf0, pb0.v, of[ct], 0, 0, 0);   \
      short8 vf1 = *(const short8*)&Sb[vc + ct * 1024 + l32 * 32 + (((2 + half) ^ sw2) * 8)]; \
      of[ct] = __builtin_amdgcn_mfma_f32_32x32x16_bf16(vf1, pb1.v, of[ct], 0, 0, 0);   \
    }                                                                             \
  }

  // slot offset rotation (u16 units within stream)
  int kc = 0, kn = 2048, kt2 = 4096;
  int vc = 6144, vn = 6144 + 8192, vt2 = 6144 + 16384;

  // prologue: stage tiles 0,1
  STAGE(0, kc, vc);
  STAGE(1, kn, vn);

  for (int t = 0; t < 63; t++) {
    asm volatile("s_waitcnt vmcnt(10)" ::: "memory");   // own tile-t DMAs landed
    __builtin_amdgcn_s_barrier();                       // partner's too
    if (t < 62) STAGE(t + 2, kt2, vt2);                 // freed slot: readers pre-barrier
    COMPUTE();
    int tk = kc; kc = kn; kn = kt2; kt2 = tk;
    int tv = vc; vc = vn; vn = vt2; vt2 = tv;
  }
  asm volatile("s_waitcnt vmcnt(0)" ::: "memory");
  __builtin_amdgcn_s_barrier();
  COMPUTE();

#undef STAGE
#undef COMPUTE

  // ---- epilogue: combine j-halves via LDS; scale; store
  lp += __shfl_xor(lp, 32);                  // both lane-halves: full l for this j-half
  __syncthreads();                           // all compute done; LDS reusable
  float* Lf = (float*)(lds + 30720);
  if (lane < 32) Lf[w * 32 + l32] = lp;
  float* Osh = (float*)(lds + qa * 30720 + 6144);   // 32 KB per qa (V areas)
  if (jh) {
#pragma unroll
    for (int ct = 0; ct < 8; ct++)
#pragma unroll
      for (int r = 0; r < 16; r++)
        Osh[(ct * 32 + (r & 3) + 8 * (r >> 2) + 4 * half) * 32 + l32] = of[ct][r];
  }
  __syncthreads();
  if (!jh) {
    const float inv = 1.0f / (Lf[qa * 32 + l32] + Lf[(2 + qa) * 32 + l32]);
    float* ob = out + (size_t)b * 256 * HW + q0 + l32;
#pragma unroll
    for (int ct = 0; ct < 8; ct++)
#pragma unroll
      for (int r = 0; r < 16; r++) {
        const int c = ct * 32 + (r & 3) + 8 * (r >> 2) + 4 * half;
        ob[(size_t)c * HW] = (of[ct][r] + Osh[c * 32 + l32]) * inv;
      }
  }
}

extern "C" void kernel_launch(void* const* d_in, const int* in_sizes, int n_in,
                              void* d_out, int out_size, void* d_ws, size_t ws_size,
                              hipStream_t stream) {
  const float* x  = (const float*)d_in[0];
  const float* qw = (const float*)d_in[1];
  const float* qb = (const float*)d_in[2];
  const float* kw = (const float*)d_in[3];
  const float* kb = (const float*)d_in[4];
  const float* vw = (const float*)d_in[5];
  const float* vb = (const float*)d_in[6];
  float* out = (float*)d_out;
  char* ws = (char*)d_ws;
  u16*   Xtp = (u16*)(ws);
  u16*   Wt  = (u16*)(ws + 8921088);
  float* bc  = (float*)(ws + 10690560);
  u16*   Qt  = (u16*)(ws + 10692096);
  u16*   Kt  = (u16*)(ws + 12789248);
  u16*   Vcf = (u16*)(ws + 14886400);

  hipMemsetAsync(Xtp, 0, 8921088, stream);  // zero the spatial halo
  k_xt  <<<dim3(128, 8, 4), 256, 0, stream>>>(x, Xtp);
  k_wprep<<<3456, 256, 0, stream>>>(qw, qb, kw, kb, vw, vb, Wt, bc);
  k_conv<<<dim3(32, 6, 4), 256, 0, stream>>>(Xtp, Wt, bc, Qt, Kt, Vcf);
  k_attn<<<256, 256, 0, stream>>>(Qt, Kt, Vcf, out);
}